// Round 1
// baseline (792.890 us; speedup 1.0000x reference)
//
#include <hip/hip_runtime.h>
#include <math.h>

#define BATCH 8
#define TENC 2048
#define TDEC 512
#define DIM 1024
#define NEG_BIG 1e20f

// Tile config shared by both GEMMs
#define BM 64
#define BN 64
#define BK 16
#define LDSS 68   // padded leading dim: 16B-aligned float4 rows, <=2-way bank alias

// ---------------------------------------------------------------------------
// GEMM1: raw[b,t,u] = dot(enc[b,t,:], dec[b,u,:]) - (1-mask[b,t])*NEG_BIG
// C = A * B^T : A = enc (TENC x DIM, k-contiguous), Bm = dec (TDEC x DIM,
// k-contiguous), C row-major (TENC x TDEC).
// ---------------------------------------------------------------------------
__global__ __launch_bounds__(256) void gemm1_kernel(
    const float* __restrict__ enc, const float* __restrict__ dec,
    const int* __restrict__ mask, float* __restrict__ raw)
{
    __shared__ float As[BK][LDSS];
    __shared__ float Bs[BK][LDSS];

    const int b   = blockIdx.z;
    const int m0  = blockIdx.y * BM;   // t offset
    const int n0  = blockIdx.x * BN;   // u offset
    const int tid = threadIdx.x;

    const float* A  = enc + (size_t)b * TENC * DIM;
    const float* Bp = dec + (size_t)b * TDEC * DIM;
    float*       C  = raw + (size_t)b * TENC * TDEC;

    // loader mapping: each thread loads one float4 of A and one of B per tile
    const int lr = tid >> 2;          // 0..63: row within tile
    const int lc = (tid & 3) * 4;     // 0,4,8,12: k offset

    // compute mapping: 16x16 threads, each 4x4 outputs
    const int tx = tid & 15;          // n dir
    const int ty = tid >> 4;          // m dir

    float acc[4][4] = {};

    for (int k0 = 0; k0 < DIM; k0 += BK) {
        float4 av = *(const float4*)(A  + (size_t)(m0 + lr) * DIM + k0 + lc);
        float4 bv = *(const float4*)(Bp + (size_t)(n0 + lr) * DIM + k0 + lc);
        __syncthreads();
        As[lc + 0][lr] = av.x; As[lc + 1][lr] = av.y;
        As[lc + 2][lr] = av.z; As[lc + 3][lr] = av.w;
        Bs[lc + 0][lr] = bv.x; Bs[lc + 1][lr] = bv.y;
        Bs[lc + 2][lr] = bv.z; Bs[lc + 3][lr] = bv.w;
        __syncthreads();
#pragma unroll
        for (int k = 0; k < BK; ++k) {
            float4 a4 = *(const float4*)&As[k][ty * 4];
            float4 b4 = *(const float4*)&Bs[k][tx * 4];
            float a[4] = {a4.x, a4.y, a4.z, a4.w};
            float bb[4] = {b4.x, b4.y, b4.z, b4.w};
#pragma unroll
            for (int i = 0; i < 4; ++i)
#pragma unroll
                for (int j = 0; j < 4; ++j)
                    acc[i][j] += a[i] * bb[j];
        }
    }

#pragma unroll
    for (int i = 0; i < 4; ++i) {
        const int t = m0 + ty * 4 + i;
        const float mk = (mask[b * TENC + t] == 0) ? NEG_BIG : 0.0f;
        float4 out;
        out.x = acc[i][0] - mk;
        out.y = acc[i][1] - mk;
        out.z = acc[i][2] - mk;
        out.w = acc[i][3] - mk;
        *(float4*)(C + (size_t)t * TDEC + n0 + tx * 4) = out;
    }
}

// ---------------------------------------------------------------------------
// Softmax over t (axis of length TENC) per (b,u) column, in place.
// Block: 256 threads = 64 u-columns x 4 t-groups. Grid: (TDEC/64, BATCH).
// ---------------------------------------------------------------------------
__global__ __launch_bounds__(256) void softmax_kernel(float* __restrict__ S)
{
    const int b  = blockIdx.y;
    const int u0 = blockIdx.x * 64;
    const int up = threadIdx.x & 63;
    const int tg = threadIdx.x >> 6;

    float* col = S + (size_t)b * TENC * TDEC + u0;

    float m = -INFINITY, s = 0.0f;
    for (int t = tg; t < TENC; t += 4) {
        float x = col[(size_t)t * TDEC + up];
        float mn = fmaxf(m, x);
        s = s * __expf(m - mn) + __expf(x - mn);
        m = mn;
    }

    __shared__ float sm[4][64];
    __shared__ float ss[4][64];
    sm[tg][up] = m;
    ss[tg][up] = s;
    __syncthreads();

    // all threads redundantly combine the 4 partials for their column
    float M = fmaxf(fmaxf(sm[0][up], sm[1][up]), fmaxf(sm[2][up], sm[3][up]));
    float Ssum = ss[0][up] * __expf(sm[0][up] - M)
               + ss[1][up] * __expf(sm[1][up] - M)
               + ss[2][up] * __expf(sm[2][up] - M)
               + ss[3][up] * __expf(sm[3][up] - M);
    float inv = 1.0f / Ssum;

    for (int t = tg; t < TENC; t += 4) {
        float x = col[(size_t)t * TDEC + up];
        col[(size_t)t * TDEC + up] = __expf(x - M) * inv;
    }
}

// ---------------------------------------------------------------------------
// GEMM2: context[b,u,d] = sum_t scores[b,t,u] * enc[b,t,d]
// C2 = A^T * B with A = scores ([k=t][m=u], m-contiguous),
// B = enc ([k=t][n=d], n-contiguous), C2 (TDEC x DIM) row-major.
// Both operands load straight into [k][m]/[k][n] LDS tiles (no transpose).
// ---------------------------------------------------------------------------
__global__ __launch_bounds__(256) void gemm2_kernel(
    const float* __restrict__ scores, const float* __restrict__ enc,
    float* __restrict__ context)
{
    __shared__ float As[BK][LDSS];
    __shared__ float Bs[BK][LDSS];

    const int b   = blockIdx.z;
    const int m0  = blockIdx.y * BM;   // u offset
    const int n0  = blockIdx.x * BN;   // d offset
    const int tid = threadIdx.x;

    const float* A  = scores + (size_t)b * TENC * TDEC;
    const float* Bp = enc    + (size_t)b * TENC * DIM;
    float*       C  = context + (size_t)b * TDEC * DIM;

    // loader mapping: 16 k-rows x (64 floats = 16 float4s)
    const int r2 = tid >> 4;          // 0..15: k row
    const int c2 = (tid & 15) * 4;    // 0..60: column offset

    const int tx = tid & 15;
    const int ty = tid >> 4;

    float acc[4][4] = {};

    for (int k0 = 0; k0 < TENC; k0 += BK) {
        float4 av = *(const float4*)(A  + (size_t)(k0 + r2) * TDEC + m0 + c2);
        float4 bv = *(const float4*)(Bp + (size_t)(k0 + r2) * DIM + n0 + c2);
        __syncthreads();
        *(float4*)&As[r2][c2] = av;
        *(float4*)&Bs[r2][c2] = bv;
        __syncthreads();
#pragma unroll
        for (int k = 0; k < BK; ++k) {
            float4 a4 = *(const float4*)&As[k][ty * 4];
            float4 b4 = *(const float4*)&Bs[k][tx * 4];
            float a[4] = {a4.x, a4.y, a4.z, a4.w};
            float bb[4] = {b4.x, b4.y, b4.z, b4.w};
#pragma unroll
            for (int i = 0; i < 4; ++i)
#pragma unroll
                for (int j = 0; j < 4; ++j)
                    acc[i][j] += a[i] * bb[j];
        }
    }

#pragma unroll
    for (int i = 0; i < 4; ++i) {
        const int u = m0 + ty * 4 + i;
        float4 out;
        out.x = acc[i][0];
        out.y = acc[i][1];
        out.z = acc[i][2];
        out.w = acc[i][3];
        *(float4*)(C + (size_t)u * DIM + n0 + tx * 4) = out;
    }
}

// ---------------------------------------------------------------------------
extern "C" void kernel_launch(void* const* d_in, const int* in_sizes, int n_in,
                              void* d_out, int out_size, void* d_ws, size_t ws_size,
                              hipStream_t stream)
{
    const float* enc      = (const float*)d_in[0];
    const int*   enc_mask = (const int*)  d_in[1];
    const float* dec      = (const float*)d_in[2];

    float* context = (float*)d_out;                       // B*TDEC*DIM floats
    float* scores  = context + (size_t)BATCH * TDEC * DIM; // B*TENC*TDEC floats

    // K1: raw masked scores -> scores region of d_out
    gemm1_kernel<<<dim3(TDEC / BN, TENC / BM, BATCH), 256, 0, stream>>>(
        enc, dec, enc_mask, scores);

    // K2: softmax over t, in place
    softmax_kernel<<<dim3(TDEC / 64, BATCH), 256, 0, stream>>>(scores);

    // K3: context = scores^T @ enc
    gemm2_kernel<<<dim3(DIM / BN, TDEC / BM, BATCH), 256, 0, stream>>>(
        scores, enc, context);
}

// Round 2
// 368.875 us; speedup vs baseline: 2.1495x; 2.1495x over previous
//
#include <hip/hip_runtime.h>
#include <math.h>

#define BATCH 8
#define TENC 2048
#define TDEC 512
#define DIM 1024
#define NEG_BIG 1e20f

typedef __attribute__((ext_vector_type(8))) short short8;
typedef __attribute__((ext_vector_type(4))) float f32x4;

// ---- fp32 -> bf16 split helpers (round-to-nearest-even on raw bits) -------
__device__ __forceinline__ unsigned int bf16rn(float x) {
    unsigned int u = __float_as_uint(x);
    return (u + 0x7FFFu + ((u >> 16) & 1u)) >> 16;
}
__device__ __forceinline__ float bf16f(unsigned int b) {
    return __uint_as_float(b << 16);
}
__device__ __forceinline__ void split2(float x, unsigned int& h, unsigned int& l) {
    h = bf16rn(x);
    l = bf16rn(x - bf16f(h));
}

// pack 8 consecutive-k fp32 into hi/lo bf16x8 and store 16B to LDS
__device__ __forceinline__ void store8(unsigned short* ph, unsigned short* pl,
                                       float4 x0, float4 x1) {
    float xs[8] = {x0.x, x0.y, x0.z, x0.w, x1.x, x1.y, x1.z, x1.w};
    short8 hv, lv;
#pragma unroll
    for (int i = 0; i < 8; ++i) {
        unsigned int h, l;
        split2(xs[i], h, l);
        hv[i] = (short)h;
        lv[i] = (short)l;
    }
    *(short8*)ph = hv;
    *(short8*)pl = lv;
}

// pack 4 consecutive-k fp32 into hi/lo bf16x4 and store 8B to LDS
__device__ __forceinline__ void wr4(unsigned short* ph, unsigned short* pl,
                                    const float* x) {
    unsigned int h[4], l[4];
#pragma unroll
    for (int i = 0; i < 4; ++i) split2(x[i], h[i], l[i]);
    uint2 hv = make_uint2(h[0] | (h[1] << 16), h[2] | (h[3] << 16));
    uint2 lv = make_uint2(l[0] | (l[1] << 16), l[2] | (l[3] << 16));
    *(uint2*)ph = hv;
    *(uint2*)pl = lv;
}

// read bf16x8 fragment from an 8B-aligned (not 16B) LDS row
__device__ __forceinline__ short8 frag8B(const unsigned short* p) {
    union { short8 v; uint2 u[2]; } f;
    f.u[0] = *(const uint2*)p;
    f.u[1] = *(const uint2*)(p + 4);
    return f.v;
}

// ---------------------------------------------------------------------------
// GEMM1 (MFMA split-bf16): raw[b,t,u] = enc[b,t,:]·dec[b,u,:] - mask
// Block tile 128(t) x 128(u), BK=32. Both operands k-contiguous in memory.
// LDS layout [row][k], stride 32 bf16 (64B) -> b128 reads/writes conflict-free.
// ---------------------------------------------------------------------------
__global__ __launch_bounds__(256) void gemm1_mfma(
    const float* __restrict__ enc, const float* __restrict__ dec,
    const int* __restrict__ mask, float* __restrict__ raw)
{
    __shared__ __align__(16) unsigned short Ah[128 * 32];
    __shared__ __align__(16) unsigned short Al[128 * 32];
    __shared__ __align__(16) unsigned short Bh[128 * 32];
    __shared__ __align__(16) unsigned short Bl[128 * 32];

    const int b  = blockIdx.z;
    const int m0 = blockIdx.y * 128;   // t
    const int n0 = blockIdx.x * 128;   // u
    const int tid = threadIdx.x;

    const float* A  = enc + (size_t)b * TENC * DIM;
    const float* Bg = dec + (size_t)b * TDEC * DIM;
    float*       C  = raw + (size_t)b * TENC * TDEC;

    const int lane = tid & 63;
    const int wv   = tid >> 6;
    const int wm   = (wv & 1) * 64;
    const int wn   = (wv >> 1) * 64;
    const int lr   = lane & 15;
    const int q    = lane >> 4;

    // staging: each thread stages 8-k chunks of rows r0 and r0+64
    const int r0 = tid >> 2;
    const int c8 = (tid & 3) * 8;

    f32x4 acc[4][4] = {};

    for (int k0 = 0; k0 < DIM; k0 += 32) {
        const float* pa0 = A  + (size_t)(m0 + r0) * DIM + k0 + c8;
        const float* pa1 = A  + (size_t)(m0 + r0 + 64) * DIM + k0 + c8;
        const float* pb0 = Bg + (size_t)(n0 + r0) * DIM + k0 + c8;
        const float* pb1 = Bg + (size_t)(n0 + r0 + 64) * DIM + k0 + c8;
        float4 a0 = *(const float4*)pa0, a0b = *(const float4*)(pa0 + 4);
        float4 a1 = *(const float4*)pa1, a1b = *(const float4*)(pa1 + 4);
        float4 b0 = *(const float4*)pb0, b0b = *(const float4*)(pb0 + 4);
        float4 b1 = *(const float4*)pb1, b1b = *(const float4*)(pb1 + 4);

        __syncthreads();
        store8(&Ah[r0 * 32 + c8],        &Al[r0 * 32 + c8],        a0, a0b);
        store8(&Ah[(r0 + 64) * 32 + c8], &Al[(r0 + 64) * 32 + c8], a1, a1b);
        store8(&Bh[r0 * 32 + c8],        &Bl[r0 * 32 + c8],        b0, b0b);
        store8(&Bh[(r0 + 64) * 32 + c8], &Bl[(r0 + 64) * 32 + c8], b1, b1b);
        __syncthreads();

        short8 ah[4], al[4], bh[4], bl[4];
#pragma unroll
        for (int i = 0; i < 4; ++i) {
            ah[i] = *(const short8*)&Ah[(wm + i * 16 + lr) * 32 + q * 8];
            al[i] = *(const short8*)&Al[(wm + i * 16 + lr) * 32 + q * 8];
            bh[i] = *(const short8*)&Bh[(wn + i * 16 + lr) * 32 + q * 8];
            bl[i] = *(const short8*)&Bl[(wn + i * 16 + lr) * 32 + q * 8];
        }
#pragma unroll
        for (int i = 0; i < 4; ++i)
#pragma unroll
            for (int j = 0; j < 4; ++j) {
                acc[i][j] = __builtin_amdgcn_mfma_f32_16x16x32_bf16(ah[i], bh[j], acc[i][j], 0, 0, 0);
                acc[i][j] = __builtin_amdgcn_mfma_f32_16x16x32_bf16(ah[i], bl[j], acc[i][j], 0, 0, 0);
                acc[i][j] = __builtin_amdgcn_mfma_f32_16x16x32_bf16(al[i], bh[j], acc[i][j], 0, 0, 0);
            }
    }

    // epilogue: C/D layout col=lane&15, row=quad*4+reg (verified m89/m91)
#pragma unroll
    for (int i = 0; i < 4; ++i) {
#pragma unroll
        for (int rr = 0; rr < 4; ++rr) {
            const int t = m0 + wm + i * 16 + q * 4 + rr;
            const float mk = (mask[b * TENC + t] == 0) ? NEG_BIG : 0.0f;
#pragma unroll
            for (int j = 0; j < 4; ++j) {
                const int u = n0 + wn + j * 16 + lr;
                C[(size_t)t * TDEC + u] = acc[i][j][rr] - mk;
            }
        }
    }
}

// ---------------------------------------------------------------------------
// Softmax over t per (b,u) column, in place. 16 u-cols x 16 t-groups/block.
// Grid (TDEC/16=32, BATCH) = 256 blocks -> full CU coverage.
// ---------------------------------------------------------------------------
__global__ __launch_bounds__(256) void softmax_kernel(float* __restrict__ S)
{
    const int b  = blockIdx.y;
    const int u0 = blockIdx.x * 16;
    const int up = threadIdx.x & 15;
    const int tg = threadIdx.x >> 4;   // 0..15

    float* col = S + (size_t)b * TENC * TDEC + u0;

    float m = -INFINITY, s = 0.0f;
    for (int t = tg; t < TENC; t += 16) {
        float x = col[(size_t)t * TDEC + up];
        float mn = fmaxf(m, x);
        s = s * __expf(m - mn) + __expf(x - mn);
        m = mn;
    }

    __shared__ float sm[16][17];
    __shared__ float ss[16][17];
    sm[tg][up] = m;
    ss[tg][up] = s;
    __syncthreads();

    float M = -INFINITY;
#pragma unroll
    for (int j = 0; j < 16; ++j) M = fmaxf(M, sm[j][up]);
    float sum = 0.0f;
#pragma unroll
    for (int j = 0; j < 16; ++j) sum += ss[j][up] * __expf(sm[j][up] - M);
    const float inv = 1.0f / sum;

    for (int t = tg; t < TENC; t += 16) {
        float x = col[(size_t)t * TDEC + up];
        col[(size_t)t * TDEC + up] = __expf(x - M) * inv;
    }
}

// ---------------------------------------------------------------------------
// GEMM2 (MFMA split-bf16): context[b,u,d] = sum_t scores[b,t,u]*enc[b,t,d]
// M=u(512), N=d(1024), K=t(2048). Both operands k(t)-major in memory ->
// transpose during staging into [row][k] LDS, stride 36 bf16 (72B, 8B-aligned
// rows: b64 fragment reads, 4-way write alias only).
// ---------------------------------------------------------------------------
#define G2_LD 36

__global__ __launch_bounds__(256) void gemm2_mfma(
    const float* __restrict__ scores, const float* __restrict__ enc,
    float* __restrict__ context)
{
    __shared__ __align__(16) unsigned short Ah[128 * G2_LD];
    __shared__ __align__(16) unsigned short Al[128 * G2_LD];
    __shared__ __align__(16) unsigned short Bh[128 * G2_LD];
    __shared__ __align__(16) unsigned short Bl[128 * G2_LD];

    const int b  = blockIdx.z;
    const int m0 = blockIdx.y * 128;   // u
    const int n0 = blockIdx.x * 128;   // d
    const int tid = threadIdx.x;

    const float* S = scores + (size_t)b * TENC * TDEC;
    const float* E = enc    + (size_t)b * TENC * DIM;
    float*       C = context + (size_t)b * TDEC * DIM;

    const int lane = tid & 63;
    const int wv   = tid >> 6;
    const int wm   = (wv & 1) * 64;
    const int wn   = (wv >> 1) * 64;
    const int lr   = lane & 15;
    const int q    = lane >> 4;

    // staging: thread owns column ul (u for A, d for B), t-half th
    const int ul = tid & 127;
    const int th = (tid >> 7) * 16;

    f32x4 acc[4][4] = {};

    for (int k0 = 0; k0 < TENC; k0 += 32) {
        float av[16], bv[16];
#pragma unroll
        for (int i = 0; i < 4; ++i) {
            const int t = k0 + th + i * 4;
#pragma unroll
            for (int j = 0; j < 4; ++j) {
                av[i * 4 + j] = S[(size_t)(t + j) * TDEC + m0 + ul];
                bv[i * 4 + j] = E[(size_t)(t + j) * DIM + n0 + ul];
            }
        }
        __syncthreads();
#pragma unroll
        for (int i = 0; i < 4; ++i) {
            const int tt = th + i * 4;
            wr4(&Ah[ul * G2_LD + tt], &Al[ul * G2_LD + tt], &av[i * 4]);
            wr4(&Bh[ul * G2_LD + tt], &Bl[ul * G2_LD + tt], &bv[i * 4]);
        }
        __syncthreads();

        short8 ah[4], al[4], bh[4], bl[4];
#pragma unroll
        for (int i = 0; i < 4; ++i) {
            ah[i] = frag8B(&Ah[(wm + i * 16 + lr) * G2_LD + q * 8]);
            al[i] = frag8B(&Al[(wm + i * 16 + lr) * G2_LD + q * 8]);
            bh[i] = frag8B(&Bh[(wn + i * 16 + lr) * G2_LD + q * 8]);
            bl[i] = frag8B(&Bl[(wn + i * 16 + lr) * G2_LD + q * 8]);
        }
#pragma unroll
        for (int i = 0; i < 4; ++i)
#pragma unroll
            for (int j = 0; j < 4; ++j) {
                acc[i][j] = __builtin_amdgcn_mfma_f32_16x16x32_bf16(ah[i], bh[j], acc[i][j], 0, 0, 0);
                acc[i][j] = __builtin_amdgcn_mfma_f32_16x16x32_bf16(ah[i], bl[j], acc[i][j], 0, 0, 0);
                acc[i][j] = __builtin_amdgcn_mfma_f32_16x16x32_bf16(al[i], bh[j], acc[i][j], 0, 0, 0);
            }
    }

#pragma unroll
    for (int i = 0; i < 4; ++i) {
#pragma unroll
        for (int rr = 0; rr < 4; ++rr) {
            const int u = m0 + wm + i * 16 + q * 4 + rr;
#pragma unroll
            for (int j = 0; j < 4; ++j) {
                const int d = n0 + wn + j * 16 + lr;
                C[(size_t)u * DIM + d] = acc[i][j][rr];
            }
        }
    }
}

// ---------------------------------------------------------------------------
extern "C" void kernel_launch(void* const* d_in, const int* in_sizes, int n_in,
                              void* d_out, int out_size, void* d_ws, size_t ws_size,
                              hipStream_t stream)
{
    const float* enc      = (const float*)d_in[0];
    const int*   enc_mask = (const int*)  d_in[1];
    const float* dec      = (const float*)d_in[2];

    float* context = (float*)d_out;                        // B*TDEC*DIM
    float* scores  = context + (size_t)BATCH * TDEC * DIM; // B*TENC*TDEC

    gemm1_mfma<<<dim3(TDEC / 128, TENC / 128, BATCH), 256, 0, stream>>>(
        enc, dec, enc_mask, scores);

    softmax_kernel<<<dim3(TDEC / 16, BATCH), 256, 0, stream>>>(scores);

    gemm2_mfma<<<dim3(DIM / 128, TDEC / 128, BATCH), 256, 0, stream>>>(
        scores, enc, context);
}

// Round 3
// 280.944 us; speedup vs baseline: 2.8222x; 1.3130x over previous
//
#include <hip/hip_runtime.h>
#include <math.h>

#define BATCH 8
#define TENC 2048
#define TDEC 512
#define DIM 1024
#define NEG_BIG 1e20f

typedef __attribute__((ext_vector_type(8))) short short8;
typedef __attribute__((ext_vector_type(4))) float f32x4;
typedef unsigned short ushort_t;

// ---- fp32 -> bf16 helpers (round-to-nearest-even on raw bits) -------------
__device__ __forceinline__ unsigned int bf16rn(float x) {
    unsigned int u = __float_as_uint(x);
    return (u + 0x7FFFu + ((u >> 16) & 1u)) >> 16;
}
__device__ __forceinline__ float bf16f(unsigned int b) {
    return __uint_as_float(b << 16);
}
__device__ __forceinline__ void split2(float x, unsigned int& h, unsigned int& l) {
    h = bf16rn(x);
    l = bf16rn(x - bf16f(h));
}

// async global(bf16 data) -> LDS, 16B per lane, wave-uniform LDS base
#define GLOAD16(g, l)                                                        \
    __builtin_amdgcn_global_load_lds(                                        \
        (const __attribute__((address_space(1))) unsigned int*)(g),          \
        (__attribute__((address_space(3))) unsigned int*)(l), 16, 0, 0)

// ===========================================================================
// PRIMARY PATH (needs ~128.2 MiB workspace)
// ===========================================================================

// ---------------------------------------------------------------------------
// prep_enc: enc fp32 [b][t][d] -> encH/encL bf16 [b][t][d] + encT bf16 [b][d][t]
// 64x64 tiles, LDS transpose for encT. Grid (DIM/64, TENC/64, BATCH).
// ---------------------------------------------------------------------------
__global__ __launch_bounds__(256) void prep_enc(
    const float* __restrict__ enc, ushort_t* __restrict__ encH,
    ushort_t* __restrict__ encL, ushort_t* __restrict__ encT)
{
    __shared__ ushort_t T[64][72];   // [d][t], stride 72 shorts = 144B (16B-aligned rows)

    const int b  = blockIdx.z;
    const int t0 = blockIdx.y * 64;
    const int d0 = blockIdx.x * 64;
    const int tid = threadIdx.x;

    const int tr = tid >> 4;          // 0..15
    const int dc = (tid & 15) * 4;    // 0..60

    const float* E = enc + (size_t)b * TENC * DIM;

#pragma unroll
    for (int i = 0; i < 4; ++i) {
        const int t = t0 + tr + 16 * i;
        float4 x = *(const float4*)&E[(size_t)t * DIM + d0 + dc];
        float xs[4] = {x.x, x.y, x.z, x.w};
        unsigned int h[4], l[4];
#pragma unroll
        for (int j = 0; j < 4; ++j) split2(xs[j], h[j], l[j]);
        ushort_t* ph = &encH[((size_t)b * TENC + t) * DIM + d0 + dc];
        ushort_t* pl = &encL[((size_t)b * TENC + t) * DIM + d0 + dc];
        *(uint2*)ph = make_uint2(h[0] | (h[1] << 16), h[2] | (h[3] << 16));
        *(uint2*)pl = make_uint2(l[0] | (l[1] << 16), l[2] | (l[3] << 16));
        const int tloc = tr + 16 * i;
#pragma unroll
        for (int j = 0; j < 4; ++j) T[dc + j][tloc] = (ushort_t)h[j];
    }
    __syncthreads();

    const int dr = tid >> 2;          // 0..63
    const int tc = (tid & 3) * 16;    // 0,16,32,48
    short8 v0 = *(const short8*)&T[dr][tc];
    short8 v1 = *(const short8*)&T[dr][tc + 8];
    ushort_t* out = &encT[((size_t)b * DIM + d0 + dr) * TENC + t0 + tc];
    *(short8*)out = v0;
    *(short8*)(out + 8) = v1;
}

// ---------------------------------------------------------------------------
// prep_dec: dec fp32 -> decH/decL bf16, same layout. One float4 per thread.
// ---------------------------------------------------------------------------
__global__ __launch_bounds__(256) void prep_dec(
    const float* __restrict__ dec, ushort_t* __restrict__ decH,
    ushort_t* __restrict__ decL)
{
    const size_t i4 = (size_t)blockIdx.x * 256 + threadIdx.x;
    float4 x = *(const float4*)(dec + i4 * 4);
    float xs[4] = {x.x, x.y, x.z, x.w};
    unsigned int h[4], l[4];
#pragma unroll
    for (int j = 0; j < 4; ++j) split2(xs[j], h[j], l[j]);
    *(uint2*)(decH + i4 * 4) = make_uint2(h[0] | (h[1] << 16), h[2] | (h[3] << 16));
    *(uint2*)(decL + i4 * 4) = make_uint2(l[0] | (l[1] << 16), l[2] | (l[3] << 16));
}

// ---------------------------------------------------------------------------
// zero_ctx: zero the context region (gemm2 accumulates with atomicAdd)
// ---------------------------------------------------------------------------
__global__ __launch_bounds__(256) void zero_ctx(float* __restrict__ ctx)
{
    const size_t i4 = (size_t)blockIdx.x * 256 + threadIdx.x;
    *(float4*)(ctx + i4 * 4) = make_float4(0.f, 0.f, 0.f, 0.f);
}

// ---------------------------------------------------------------------------
// gemm1_lds: raw[b,t,u] = enc·dec (split-bf16, 3 MFMA terms) - mask
// m97 structure: 128x128 tile, BK=32, global_load_lds staging, no conversion.
// ---------------------------------------------------------------------------
__global__ __launch_bounds__(256) void gemm1_lds(
    const ushort_t* __restrict__ encH, const ushort_t* __restrict__ encL,
    const ushort_t* __restrict__ decH, const ushort_t* __restrict__ decL,
    const int* __restrict__ mask, float* __restrict__ raw)
{
    __shared__ __align__(16) ushort_t Ah[128 * 32];
    __shared__ __align__(16) ushort_t Al[128 * 32];
    __shared__ __align__(16) ushort_t Bh[128 * 32];
    __shared__ __align__(16) ushort_t Bl[128 * 32];

    const int b  = blockIdx.z;
    const int m0 = blockIdx.y * 128;   // t
    const int n0 = blockIdx.x * 128;   // u
    const int tid = threadIdx.x;

    const int lane = tid & 63;
    const int w    = tid >> 6;
    const int wm   = (w & 1) * 64;
    const int wn   = (w >> 1) * 64;
    const int lr   = lane & 15;
    const int q    = lane >> 4;

    const int srow = lane >> 2;        // 0..15 row within 16-row group
    const int scol = (lane & 3) * 8;   // shorts (16B chunks)

    const ushort_t* AH = encH + (size_t)b * TENC * DIM;
    const ushort_t* AL = encL + (size_t)b * TENC * DIM;
    const ushort_t* BH = decH + (size_t)b * TDEC * DIM;
    const ushort_t* BL = decL + (size_t)b * TDEC * DIM;
    float* C = raw + (size_t)b * TENC * TDEC;

    f32x4 acc[4][4] = {};

    for (int k0 = 0; k0 < DIM; k0 += 32) {
        __syncthreads();
#pragma unroll
        for (int q2 = 0; q2 < 2; ++q2) {
            const int rg  = w * 2 + q2;            // 16-row group 0..7
            const int row = rg * 16 + srow;
            const size_t ga = (size_t)(m0 + row) * DIM + k0 + scol;
            const size_t gb = (size_t)(n0 + row) * DIM + k0 + scol;
            GLOAD16(AH + ga, &Ah[rg * 16 * 32]);
            GLOAD16(AL + ga, &Al[rg * 16 * 32]);
            GLOAD16(BH + gb, &Bh[rg * 16 * 32]);
            GLOAD16(BL + gb, &Bl[rg * 16 * 32]);
        }
        __syncthreads();

        short8 ah[4], al[4], bh[4], bl[4];
#pragma unroll
        for (int i = 0; i < 4; ++i) {
            ah[i] = *(const short8*)&Ah[(wm + i * 16 + lr) * 32 + q * 8];
            al[i] = *(const short8*)&Al[(wm + i * 16 + lr) * 32 + q * 8];
            bh[i] = *(const short8*)&Bh[(wn + i * 16 + lr) * 32 + q * 8];
            bl[i] = *(const short8*)&Bl[(wn + i * 16 + lr) * 32 + q * 8];
        }
#pragma unroll
        for (int i = 0; i < 4; ++i)
#pragma unroll
            for (int j = 0; j < 4; ++j) {
                acc[i][j] = __builtin_amdgcn_mfma_f32_16x16x32_bf16(ah[i], bh[j], acc[i][j], 0, 0, 0);
                acc[i][j] = __builtin_amdgcn_mfma_f32_16x16x32_bf16(ah[i], bl[j], acc[i][j], 0, 0, 0);
                acc[i][j] = __builtin_amdgcn_mfma_f32_16x16x32_bf16(al[i], bh[j], acc[i][j], 0, 0, 0);
            }
    }

    // C/D layout: col=lane&15, row=quad*4+reg
#pragma unroll
    for (int i = 0; i < 4; ++i) {
#pragma unroll
        for (int rr = 0; rr < 4; ++rr) {
            const int t = m0 + wm + i * 16 + q * 4 + rr;
            const float mk = (mask[b * TENC + t] == 0) ? NEG_BIG : 0.0f;
#pragma unroll
            for (int j = 0; j < 4; ++j) {
                const int u = n0 + wn + j * 16 + lr;
                C[(size_t)t * TDEC + u] = acc[i][j][rr] - mk;
            }
        }
    }
}

// ---------------------------------------------------------------------------
// colstat: per (b,u) online (max,sum) over a 512-t quarter. Grid (32, 8, 4).
// ---------------------------------------------------------------------------
__global__ __launch_bounds__(256) void colstat(
    const float* __restrict__ S, float* __restrict__ pm, float* __restrict__ ps)
{
    const int b  = blockIdx.y;
    const int u0 = blockIdx.x * 16;
    const int z  = blockIdx.z;
    const int up = threadIdx.x & 15;
    const int tg = threadIdx.x >> 4;

    const float* col = S + (size_t)b * TENC * TDEC + u0;
    const int t0 = z * 512;

    float m = -INFINITY, s = 0.0f;
    for (int t = t0 + tg; t < t0 + 512; t += 16) {
        float x = col[(size_t)t * TDEC + up];
        float mn = fmaxf(m, x);
        s = s * __expf(m - mn) + __expf(x - mn);
        m = mn;
    }

    __shared__ float sm[16][17];
    __shared__ float ss[16][17];
    sm[tg][up] = m;
    ss[tg][up] = s;
    __syncthreads();

    if (tg == 0) {
        float M = -INFINITY;
#pragma unroll
        for (int j = 0; j < 16; ++j) M = fmaxf(M, sm[j][up]);
        float sum = 0.0f;
#pragma unroll
        for (int j = 0; j < 16; ++j) sum += ss[j][up] * __expf(sm[j][up] - M);
        const int idx = z * (BATCH * TDEC) + b * TDEC + u0 + up;
        pm[idx] = M;
        ps[idx] = sum;
    }
}

// combine 4 quarters -> colM (max), colI (1/sum). 4096 columns.
__global__ __launch_bounds__(256) void colstat2(
    const float* __restrict__ pm, const float* __restrict__ ps,
    float* __restrict__ colM, float* __restrict__ colI)
{
    const int idx = blockIdx.x * 256 + threadIdx.x;   // b*TDEC+u
    float M = -INFINITY;
#pragma unroll
    for (int z = 0; z < 4; ++z) M = fmaxf(M, pm[z * (BATCH * TDEC) + idx]);
    float s = 0.0f;
#pragma unroll
    for (int z = 0; z < 4; ++z)
        s += ps[z * (BATCH * TDEC) + idx] * __expf(pm[z * (BATCH * TDEC) + idx] - M);
    colM[idx] = M;
    colI[idx] = 1.0f / s;
}

// ---------------------------------------------------------------------------
// norm: scores[t][u] = exp(raw-M)*inv (in place, fp32) + scoresT bf16 [u][t].
// 64x64 tiles, LDS transpose. Grid (TENC/64, TDEC/64, BATCH).
// ---------------------------------------------------------------------------
__global__ __launch_bounds__(256) void norm_kernel(
    float* __restrict__ S, const float* __restrict__ colM,
    const float* __restrict__ colI, ushort_t* __restrict__ scoresT)
{
    __shared__ ushort_t T[64][72];   // [u][t]

    const int b  = blockIdx.z;
    const int t0 = blockIdx.x * 64;
    const int u0 = blockIdx.y * 64;
    const int tid = threadIdx.x;

    const int tr  = tid >> 4;         // 0..15
    const int ucl = (tid & 15) * 4;   // 0..60

    float4 M4 = *(const float4*)&colM[b * TDEC + u0 + ucl];
    float4 I4 = *(const float4*)&colI[b * TDEC + u0 + ucl];

    float* base = S + (size_t)b * TENC * TDEC;

#pragma unroll
    for (int i = 0; i < 4; ++i) {
        const int t = t0 + tr + 16 * i;
        float4 x = *(const float4*)&base[(size_t)t * TDEC + u0 + ucl];
        float4 p;
        p.x = __expf(x.x - M4.x) * I4.x;
        p.y = __expf(x.y - M4.y) * I4.y;
        p.z = __expf(x.z - M4.z) * I4.z;
        p.w = __expf(x.w - M4.w) * I4.w;
        *(float4*)&base[(size_t)t * TDEC + u0 + ucl] = p;
        const int tloc = tr + 16 * i;
        T[ucl + 0][tloc] = (ushort_t)bf16rn(p.x);
        T[ucl + 1][tloc] = (ushort_t)bf16rn(p.y);
        T[ucl + 2][tloc] = (ushort_t)bf16rn(p.z);
        T[ucl + 3][tloc] = (ushort_t)bf16rn(p.w);
    }
    __syncthreads();

    const int ur = tid >> 2;          // 0..63
    const int tc = (tid & 3) * 16;    // 0,16,32,48
    short8 v0 = *(const short8*)&T[ur][tc];
    short8 v1 = *(const short8*)&T[ur][tc + 8];
    ushort_t* out = &scoresT[((size_t)b * TDEC + u0 + ur) * TENC + t0 + tc];
    *(short8*)out = v0;
    *(short8*)(out + 8) = v1;
}

// ---------------------------------------------------------------------------
// gemm2_lds: context[b,u,d] += sum_t scoresT[b,u,t]*encT[b,d,t]  (bf16 single)
// 128x128 tile, BK=32, split-K=2 with atomicAdd epilogue. Grid (8, 4, 16).
// ---------------------------------------------------------------------------
__global__ __launch_bounds__(256) void gemm2_lds(
    const ushort_t* __restrict__ scoresT, const ushort_t* __restrict__ encT,
    float* __restrict__ context)
{
    __shared__ __align__(16) ushort_t Ah[128 * 32];
    __shared__ __align__(16) ushort_t Bh[128 * 32];

    const int b  = blockIdx.z >> 1;
    const int ks = blockIdx.z & 1;
    const int m0 = blockIdx.y * 128;   // u
    const int n0 = blockIdx.x * 128;   // d
    const int tid = threadIdx.x;

    const int lane = tid & 63;
    const int w    = tid >> 6;
    const int wm   = (w & 1) * 64;
    const int wn   = (w >> 1) * 64;
    const int lr   = lane & 15;
    const int q    = lane >> 4;

    const int srow = lane >> 2;
    const int scol = (lane & 3) * 8;

    const ushort_t* A = scoresT + (size_t)b * TDEC * TENC;
    const ushort_t* B = encT    + (size_t)b * DIM * TENC;
    float* C = context + (size_t)b * TDEC * DIM;

    const int kbeg = ks * (TENC / 2);
    const int kend = kbeg + TENC / 2;

    f32x4 acc[4][4] = {};

    for (int k0 = kbeg; k0 < kend; k0 += 32) {
        __syncthreads();
#pragma unroll
        for (int q2 = 0; q2 < 2; ++q2) {
            const int rg  = w * 2 + q2;
            const int row = rg * 16 + srow;
            GLOAD16(A + (size_t)(m0 + row) * TENC + k0 + scol, &Ah[rg * 16 * 32]);
            GLOAD16(B + (size_t)(n0 + row) * TENC + k0 + scol, &Bh[rg * 16 * 32]);
        }
        __syncthreads();

        short8 ah[4], bh[4];
#pragma unroll
        for (int i = 0; i < 4; ++i) {
            ah[i] = *(const short8*)&Ah[(wm + i * 16 + lr) * 32 + q * 8];
            bh[i] = *(const short8*)&Bh[(wn + i * 16 + lr) * 32 + q * 8];
        }
#pragma unroll
        for (int i = 0; i < 4; ++i)
#pragma unroll
            for (int j = 0; j < 4; ++j)
                acc[i][j] = __builtin_amdgcn_mfma_f32_16x16x32_bf16(ah[i], bh[j], acc[i][j], 0, 0, 0);
    }

#pragma unroll
    for (int i = 0; i < 4; ++i)
#pragma unroll
        for (int rr = 0; rr < 4; ++rr) {
            const int u = m0 + wm + i * 16 + q * 4 + rr;
#pragma unroll
            for (int j = 0; j < 4; ++j) {
                const int d = n0 + wn + j * 16 + lr;
                atomicAdd(&C[(size_t)u * DIM + d], acc[i][j][rr]);
            }
        }
}

// ===========================================================================
// FALLBACK PATH (round-2 proven kernels; used if workspace is too small)
// ===========================================================================

__device__ __forceinline__ void store8(ushort_t* ph, ushort_t* pl,
                                       float4 x0, float4 x1) {
    float xs[8] = {x0.x, x0.y, x0.z, x0.w, x1.x, x1.y, x1.z, x1.w};
    short8 hv, lv;
#pragma unroll
    for (int i = 0; i < 8; ++i) {
        unsigned int h, l;
        split2(xs[i], h, l);
        hv[i] = (short)h;
        lv[i] = (short)l;
    }
    *(short8*)ph = hv;
    *(short8*)pl = lv;
}

__device__ __forceinline__ void wr4(ushort_t* ph, ushort_t* pl, const float* x) {
    unsigned int h[4], l[4];
#pragma unroll
    for (int i = 0; i < 4; ++i) split2(x[i], h[i], l[i]);
    *(uint2*)ph = make_uint2(h[0] | (h[1] << 16), h[2] | (h[3] << 16));
    *(uint2*)pl = make_uint2(l[0] | (l[1] << 16), l[2] | (l[3] << 16));
}

__device__ __forceinline__ short8 frag8B(const ushort_t* p) {
    union { short8 v; uint2 u[2]; } f;
    f.u[0] = *(const uint2*)p;
    f.u[1] = *(const uint2*)(p + 4);
    return f.v;
}

__global__ __launch_bounds__(256) void gemm1_mfma(
    const float* __restrict__ enc, const float* __restrict__ dec,
    const int* __restrict__ mask, float* __restrict__ raw)
{
    __shared__ __align__(16) ushort_t Ah[128 * 32];
    __shared__ __align__(16) ushort_t Al[128 * 32];
    __shared__ __align__(16) ushort_t Bh[128 * 32];
    __shared__ __align__(16) ushort_t Bl[128 * 32];

    const int b  = blockIdx.z;
    const int m0 = blockIdx.y * 128;
    const int n0 = blockIdx.x * 128;
    const int tid = threadIdx.x;

    const float* A  = enc + (size_t)b * TENC * DIM;
    const float* Bg = dec + (size_t)b * TDEC * DIM;
    float*       C  = raw + (size_t)b * TENC * TDEC;

    const int lane = tid & 63;
    const int wv   = tid >> 6;
    const int wm   = (wv & 1) * 64;
    const int wn   = (wv >> 1) * 64;
    const int lr   = lane & 15;
    const int q    = lane >> 4;

    const int r0 = tid >> 2;
    const int c8 = (tid & 3) * 8;

    f32x4 acc[4][4] = {};

    for (int k0 = 0; k0 < DIM; k0 += 32) {
        const float* pa0 = A  + (size_t)(m0 + r0) * DIM + k0 + c8;
        const float* pa1 = A  + (size_t)(m0 + r0 + 64) * DIM + k0 + c8;
        const float* pb0 = Bg + (size_t)(n0 + r0) * DIM + k0 + c8;
        const float* pb1 = Bg + (size_t)(n0 + r0 + 64) * DIM + k0 + c8;
        float4 a0 = *(const float4*)pa0, a0b = *(const float4*)(pa0 + 4);
        float4 a1 = *(const float4*)pa1, a1b = *(const float4*)(pa1 + 4);
        float4 b0 = *(const float4*)pb0, b0b = *(const float4*)(pb0 + 4);
        float4 b1 = *(const float4*)pb1, b1b = *(const float4*)(pb1 + 4);

        __syncthreads();
        store8(&Ah[r0 * 32 + c8],        &Al[r0 * 32 + c8],        a0, a0b);
        store8(&Ah[(r0 + 64) * 32 + c8], &Al[(r0 + 64) * 32 + c8], a1, a1b);
        store8(&Bh[r0 * 32 + c8],        &Bl[r0 * 32 + c8],        b0, b0b);
        store8(&Bh[(r0 + 64) * 32 + c8], &Bl[(r0 + 64) * 32 + c8], b1, b1b);
        __syncthreads();

        short8 ah[4], al[4], bh[4], bl[4];
#pragma unroll
        for (int i = 0; i < 4; ++i) {
            ah[i] = *(const short8*)&Ah[(wm + i * 16 + lr) * 32 + q * 8];
            al[i] = *(const short8*)&Al[(wm + i * 16 + lr) * 32 + q * 8];
            bh[i] = *(const short8*)&Bh[(wn + i * 16 + lr) * 32 + q * 8];
            bl[i] = *(const short8*)&Bl[(wn + i * 16 + lr) * 32 + q * 8];
        }
#pragma unroll
        for (int i = 0; i < 4; ++i)
#pragma unroll
            for (int j = 0; j < 4; ++j) {
                acc[i][j] = __builtin_amdgcn_mfma_f32_16x16x32_bf16(ah[i], bh[j], acc[i][j], 0, 0, 0);
                acc[i][j] = __builtin_amdgcn_mfma_f32_16x16x32_bf16(ah[i], bl[j], acc[i][j], 0, 0, 0);
                acc[i][j] = __builtin_amdgcn_mfma_f32_16x16x32_bf16(al[i], bh[j], acc[i][j], 0, 0, 0);
            }
    }

#pragma unroll
    for (int i = 0; i < 4; ++i)
#pragma unroll
        for (int rr = 0; rr < 4; ++rr) {
            const int t = m0 + wm + i * 16 + q * 4 + rr;
            const float mk = (mask[b * TENC + t] == 0) ? NEG_BIG : 0.0f;
#pragma unroll
            for (int j = 0; j < 4; ++j) {
                const int u = n0 + wn + j * 16 + lr;
                C[(size_t)t * TDEC + u] = acc[i][j][rr] - mk;
            }
        }
}

__global__ __launch_bounds__(256) void softmax_kernel(float* __restrict__ S)
{
    const int b  = blockIdx.y;
    const int u0 = blockIdx.x * 16;
    const int up = threadIdx.x & 15;
    const int tg = threadIdx.x >> 4;

    float* col = S + (size_t)b * TENC * TDEC + u0;

    float m = -INFINITY, s = 0.0f;
    for (int t = tg; t < TENC; t += 16) {
        float x = col[(size_t)t * TDEC + up];
        float mn = fmaxf(m, x);
        s = s * __expf(m - mn) + __expf(x - mn);
        m = mn;
    }

    __shared__ float sm[16][17];
    __shared__ float ss[16][17];
    sm[tg][up] = m;
    ss[tg][up] = s;
    __syncthreads();

    float M = -INFINITY;
#pragma unroll
    for (int j = 0; j < 16; ++j) M = fmaxf(M, sm[j][up]);
    float sum = 0.0f;
#pragma unroll
    for (int j = 0; j < 16; ++j) sum += ss[j][up] * __expf(sm[j][up] - M);
    const float inv = 1.0f / sum;

    for (int t = tg; t < TENC; t += 16) {
        float x = col[(size_t)t * TDEC + up];
        col[(size_t)t * TDEC + up] = __expf(x - M) * inv;
    }
}

#define G2_LD 36

__global__ __launch_bounds__(256) void gemm2_mfma(
    const float* __restrict__ scores, const float* __restrict__ enc,
    float* __restrict__ context)
{
    __shared__ __align__(16) ushort_t Ah[128 * G2_LD];
    __shared__ __align__(16) ushort_t Al[128 * G2_LD];
    __shared__ __align__(16) ushort_t Bh[128 * G2_LD];
    __shared__ __align__(16) ushort_t Bl[128 * G2_LD];

    const int b  = blockIdx.z;
    const int m0 = blockIdx.y * 128;
    const int n0 = blockIdx.x * 128;
    const int tid = threadIdx.x;

    const float* S = scores + (size_t)b * TENC * TDEC;
    const float* E = enc    + (size_t)b * TENC * DIM;
    float*       C = context + (size_t)b * TDEC * DIM;

    const int lane = tid & 63;
    const int wv   = tid >> 6;
    const int wm   = (wv & 1) * 64;
    const int wn   = (wv >> 1) * 64;
    const int lr   = lane & 15;
    const int q    = lane >> 4;

    const int ul = tid & 127;
    const int th = (tid >> 7) * 16;

    f32x4 acc[4][4] = {};

    for (int k0 = 0; k0 < TENC; k0 += 32) {
        float av[16], bv[16];
#pragma unroll
        for (int i = 0; i < 4; ++i) {
            const int t = k0 + th + i * 4;
#pragma unroll
            for (int j = 0; j < 4; ++j) {
                av[i * 4 + j] = S[(size_t)(t + j) * TDEC + m0 + ul];
                bv[i * 4 + j] = E[(size_t)(t + j) * DIM + n0 + ul];
            }
        }
        __syncthreads();
#pragma unroll
        for (int i = 0; i < 4; ++i) {
            const int tt = th + i * 4;
            wr4(&Ah[ul * G2_LD + tt], &Al[ul * G2_LD + tt], &av[i * 4]);
            wr4(&Bh[ul * G2_LD + tt], &Bl[ul * G2_LD + tt], &bv[i * 4]);
        }
        __syncthreads();

        short8 ah[4], al[4], bh[4], bl[4];
#pragma unroll
        for (int i = 0; i < 4; ++i) {
            ah[i] = frag8B(&Ah[(wm + i * 16 + lr) * G2_LD + q * 8]);
            al[i] = frag8B(&Al[(wm + i * 16 + lr) * G2_LD + q * 8]);
            bh[i] = frag8B(&Bh[(wn + i * 16 + lr) * G2_LD + q * 8]);
            bl[i] = frag8B(&Bl[(wn + i * 16 + lr) * G2_LD + q * 8]);
        }
#pragma unroll
        for (int i = 0; i < 4; ++i)
#pragma unroll
            for (int j = 0; j < 4; ++j) {
                acc[i][j] = __builtin_amdgcn_mfma_f32_16x16x32_bf16(ah[i], bh[j], acc[i][j], 0, 0, 0);
                acc[i][j] = __builtin_amdgcn_mfma_f32_16x16x32_bf16(ah[i], bl[j], acc[i][j], 0, 0, 0);
                acc[i][j] = __builtin_amdgcn_mfma_f32_16x16x32_bf16(al[i], bh[j], acc[i][j], 0, 0, 0);
            }
    }

#pragma unroll
    for (int i = 0; i < 4; ++i)
#pragma unroll
        for (int rr = 0; rr < 4; ++rr) {
            const int u = m0 + wm + i * 16 + q * 4 + rr;
#pragma unroll
            for (int j = 0; j < 4; ++j) {
                const int d = n0 + wn + j * 16 + lr;
                C[(size_t)u * DIM + d] = acc[i][j][rr];
            }
        }
}

// ===========================================================================
extern "C" void kernel_launch(void* const* d_in, const int* in_sizes, int n_in,
                              void* d_out, int out_size, void* d_ws, size_t ws_size,
                              hipStream_t stream)
{
    const float* enc      = (const float*)d_in[0];
    const int*   enc_mask = (const int*)  d_in[1];
    const float* dec      = (const float*)d_in[2];

    float* context = (float*)d_out;                        // B*TDEC*DIM
    float* scores  = context + (size_t)BATCH * TDEC * DIM; // B*TENC*TDEC

    // workspace layout (bytes)
    const size_t OFF_ENC_H = 0;
    const size_t OFF_ENC_L = 33554432;
    const size_t OFF_DEC_H = 67108864;
    const size_t OFF_DEC_L = 75497472;
    const size_t OFF_ENC_T = 83886080;
    const size_t OFF_SCO_T = 117440512;
    const size_t OFF_COL_M = 134217728;
    const size_t OFF_COL_I = 134234112;
    const size_t OFF_PM    = 134250496;
    const size_t OFF_PS    = 134316032;
    const size_t WS_NEED   = 134381568;

    if (ws_size >= WS_NEED) {
        char* w = (char*)d_ws;
        ushort_t* encH    = (ushort_t*)(w + OFF_ENC_H);
        ushort_t* encL    = (ushort_t*)(w + OFF_ENC_L);
        ushort_t* decH    = (ushort_t*)(w + OFF_DEC_H);
        ushort_t* decL    = (ushort_t*)(w + OFF_DEC_L);
        ushort_t* encT    = (ushort_t*)(w + OFF_ENC_T);
        ushort_t* scoresT = (ushort_t*)(w + OFF_SCO_T);
        float*    colM    = (float*)(w + OFF_COL_M);
        float*    colI    = (float*)(w + OFF_COL_I);
        float*    pm      = (float*)(w + OFF_PM);
        float*    ps      = (float*)(w + OFF_PS);

        prep_enc<<<dim3(DIM / 64, TENC / 64, BATCH), 256, 0, stream>>>(
            enc, encH, encL, encT);
        prep_dec<<<4096, 256, 0, stream>>>(dec, decH, decL);
        zero_ctx<<<4096, 256, 0, stream>>>(context);

        gemm1_lds<<<dim3(TDEC / 128, TENC / 128, BATCH), 256, 0, stream>>>(
            encH, encL, decH, decL, enc_mask, scores);

        colstat<<<dim3(TDEC / 16, BATCH, 4), 256, 0, stream>>>(scores, pm, ps);
        colstat2<<<16, 256, 0, stream>>>(pm, ps, colM, colI);

        norm_kernel<<<dim3(TENC / 64, TDEC / 64, BATCH), 256, 0, stream>>>(
            scores, colM, colI, scoresT);

        gemm2_lds<<<dim3(DIM / 128, TDEC / 128, BATCH * 2), 256, 0, stream>>>(
            scoresT, encT, context);
    } else {
        // fallback: round-2 proven path, no workspace
        gemm1_mfma<<<dim3(TDEC / 128, TENC / 128, BATCH), 256, 0, stream>>>(
            enc, dec, enc_mask, scores);
        softmax_kernel<<<dim3(TDEC / 16, BATCH), 256, 0, stream>>>(scores);
        gemm2_mfma<<<dim3(DIM / 128, TDEC / 128, BATCH), 256, 0, stream>>>(
            scores, enc, context);
    }
}